// Round 2
// baseline (713.588 us; speedup 1.0000x reference)
//
#include <hip/hip_runtime.h>
#include <hip/hip_bf16.h>

// Problem constants (fixed by the reference):
#define NB 16        // batch
#define NN 5000      // nodes
#define NF 64        // in features
#define NH 32        // hidden
#define NE 160000    // edges (without self loops)
#define NP 512       // policy hidden
#define NA 16        // actions
#define KCH 250      // K-chunks for big GEMM
#define KLEN 640     // K per chunk (250*640 = 160000)

// ---------------- CSR build ----------------
// edge_index is int32 on device (JAX default x64-disabled; harness passes int*).

__global__ __launch_bounds__(256) void k_hist(const int* __restrict__ ei,
                                              int* __restrict__ deg) {
    int e = blockIdx.x * 256 + threadIdx.x;
    if (e < NE) atomicAdd(&deg[ei[NE + e]], 1);
}

__global__ __launch_bounds__(1024) void k_scan(const int* __restrict__ deg,
                                               int* __restrict__ offs,
                                               int* __restrict__ cursor,
                                               float* __restrict__ dinv) {
    __shared__ int sm[1024];
    int t = threadIdx.x;
    int v[5]; int sum = 0;
    int base = t * 5;
#pragma unroll
    for (int i = 0; i < 5; ++i) {
        int idx = base + i;
        int d = (idx < NN) ? deg[idx] : 0;
        v[i] = d; sum += d;
    }
    sm[t] = sum; __syncthreads();
    for (int off = 1; off < 1024; off <<= 1) {
        int x = (t >= off) ? sm[t - off] : 0;
        __syncthreads();
        sm[t] += x;
        __syncthreads();
    }
    int excl = (t == 0) ? 0 : sm[t - 1];
#pragma unroll
    for (int i = 0; i < 5; ++i) {
        int idx = base + i;
        if (idx < NN) {
            offs[idx] = excl; cursor[idx] = excl;
            dinv[idx] = 1.0f / sqrtf((float)(v[i] + 1));  // +1 self loop
            excl += v[i];
        }
    }
    if (t == 1023) offs[NN] = sm[1023];
}

__global__ __launch_bounds__(256) void k_fill(const int* __restrict__ ei,
                                              const float* __restrict__ dinv,
                                              int* __restrict__ cursor,
                                              int2* __restrict__ pack) {
    int e = blockIdx.x * 256 + threadIdx.x;
    if (e < NE) {
        int s = ei[e];
        int d = ei[NE + e];
        float nrm = dinv[s] * dinv[d];
        int pos = atomicAdd(&cursor[d], 1);
        pack[pos] = make_int2(s, __float_as_int(nrm));
    }
}

// ---------------- Layer 1 transform: xw[b][n][h] = feat[b][n][:] @ W1 ----------------

__global__ __launch_bounds__(256) void k_xform1(const float* __restrict__ feat,
                                                const float* __restrict__ W1,
                                                float* __restrict__ xw) {
    __shared__ float w1s[NF * NH];   // 8 KB, same layout as global
    int t = threadIdx.x;
    for (int i = t; i < NF * NH; i += 256) w1s[i] = W1[i];
    __syncthreads();
    int h = t & 31;
    int rg = t >> 5;                         // 0..7
    int r0 = blockIdx.x * 32 + rg * 4;       // 4 rows per thread, rows = b*NN+n
    const float4* f4 = (const float4*)feat;  // row r -> f4[r*16 + q]
    float acc0 = 0.f, acc1 = 0.f, acc2 = 0.f, acc3 = 0.f;
#pragma unroll
    for (int q = 0; q < 16; ++q) {
        float4 a0 = f4[(size_t)(r0 + 0) * 16 + q];
        float4 a1 = f4[(size_t)(r0 + 1) * 16 + q];
        float4 a2 = f4[(size_t)(r0 + 2) * 16 + q];
        float4 a3 = f4[(size_t)(r0 + 3) * 16 + q];
        float w0 = w1s[(q * 4 + 0) * NH + h];
        float w1_ = w1s[(q * 4 + 1) * NH + h];
        float w2_ = w1s[(q * 4 + 2) * NH + h];
        float w3_ = w1s[(q * 4 + 3) * NH + h];
        acc0 += a0.x * w0; acc0 += a0.y * w1_; acc0 += a0.z * w2_; acc0 += a0.w * w3_;
        acc1 += a1.x * w0; acc1 += a1.y * w1_; acc1 += a1.z * w2_; acc1 += a1.w * w3_;
        acc2 += a2.x * w0; acc2 += a2.y * w1_; acc2 += a2.z * w2_; acc2 += a2.w * w3_;
        acc3 += a3.x * w0; acc3 += a3.y * w1_; acc3 += a3.z * w2_; acc3 += a3.w * w3_;
    }
    xw[(size_t)(r0 + 0) * NH + h] = acc0;
    xw[(size_t)(r0 + 1) * NH + h] = acc1;
    xw[(size_t)(r0 + 2) * NH + h] = acc2;
    xw[(size_t)(r0 + 3) * NH + h] = acc3;
}

// ---------------- Aggregation (layer 1): out = relu(agg(xw) + b1) ----------------
// grid 20000: xcd-swizzled (batch, node-group-of-4); wave per (b,n); lane: h=lane&31, half=lane>>5

__device__ __forceinline__ void agg_decode(int bid, int tid, int& b, int& n,
                                           int& hp, int& half) {
    int xcd = bid & 7;
    int g = bid >> 3;                 // 0..2499
    int hi = (g >= 1250) ? 1 : 0;
    b = xcd * 2 + hi;
    int ng = g - hi * 1250;           // 0..1249
    int w = tid >> 6;                 // 0..3
    n = ng * 4 + w;
    int lane = tid & 63;
    hp = lane & 31;
    half = lane >> 5;
}

__global__ __launch_bounds__(256) void k_agg1(const float* __restrict__ xw,
                                              const int* __restrict__ offs,
                                              const float* __restrict__ dinv,
                                              const int2* __restrict__ pack,
                                              const float* __restrict__ b1,
                                              float* __restrict__ out) {
    int b, n, hp, half;
    agg_decode(blockIdx.x, threadIdx.x, b, n, hp, half);
    const float* inb = xw + (size_t)b * (NN * NH);
    int s0 = offs[n], s1 = offs[n + 1];
    float acc = 0.f;
    for (int e = s0 + half; e < s1; e += 2) {
        int2 p = pack[e];
        acc += __int_as_float(p.y) * inb[(size_t)p.x * NH + hp];
    }
    acc += __shfl_xor(acc, 32);
    float di = dinv[n];
    float v = acc + di * di * inb[(size_t)n * NH + hp] + b1[hp];
    v = fmaxf(v, 0.f);
    if ((threadIdx.x & 63) < 32)
        out[(size_t)b * (NN * NH) + (size_t)n * NH + hp] = v;
}

// ---------------- Aggregation (layer 2) fused with @W2 + b2 + relu ----------------
// agg(h1 @ W2) == agg(h1) @ W2  (aggregation is linear over the feature dim)

__global__ __launch_bounds__(256) void k_agg2(const float* __restrict__ h1,
                                              const int* __restrict__ offs,
                                              const float* __restrict__ dinv,
                                              const int2* __restrict__ pack,
                                              const float* __restrict__ W2,
                                              const float* __restrict__ b2,
                                              float* __restrict__ h2) {
    int b, n, hp, half;
    agg_decode(blockIdx.x, threadIdx.x, b, n, hp, half);
    // W2 column hp into registers (L1-hot, 4 KB total)
    float w2c[NH];
#pragma unroll
    for (int kh = 0; kh < NH; ++kh) w2c[kh] = W2[kh * NH + hp];
    const float* inb = h1 + (size_t)b * (NN * NH);
    int s0 = offs[n], s1 = offs[n + 1];
    float acc = 0.f;
    for (int e = s0 + half; e < s1; e += 2) {
        int2 p = pack[e];
        acc += __int_as_float(p.y) * inb[(size_t)p.x * NH + hp];
    }
    acc += __shfl_xor(acc, 32);
    float di = dinv[n];
    float aggv = acc + di * di * inb[(size_t)n * NH + hp];   // pre-transform agg, valid on all lanes
    float o = b2[hp];
#pragma unroll
    for (int kh = 0; kh < NH; ++kh) {
        float av = __uint_as_float(__builtin_amdgcn_readlane(__float_as_uint(aggv), kh));
        o += av * w2c[kh];
    }
    o = fmaxf(o, 0.f);
    if ((threadIdx.x & 63) < 32)
        h2[(size_t)b * (NN * NH) + (size_t)n * NH + hp] = o;
}

// ---------------- Big GEMM: partials[ch][16][512] = flat[16][Kch] @ Wp1[Kch][512] ----------------

__global__ __launch_bounds__(512) void k_gemm1(const float* __restrict__ flat,
                                               const float* __restrict__ Wp1,
                                               float* __restrict__ part) {
    __shared__ __align__(16) float sT[64 * 20];  // [kk][m] with pad 20 (16B-aligned rows)
    int t = threadIdx.x;
    int c4 = t & 127;          // cols 4*c4 .. 4*c4+3
    int mq = t >> 7;           // 0..3 -> rows mq*4..+4
    int lane = t & 63;
    int r2 = t >> 6;           // 0..7 -> stages rows r2*2, r2*2+1
    int k0 = blockIdx.x * KLEN;
    float acc[4][4] = {{0.f}};
    for (int sub = 0; sub < KLEN / 64; ++sub) {
        int kb = k0 + sub * 64;
#pragma unroll
        for (int i = 0; i < 2; ++i) {
            int m = r2 * 2 + i;
            sT[lane * 20 + m] = flat[(size_t)m * (NN * NH) + kb + lane];
        }
        __syncthreads();
#pragma unroll 4
        for (int kk = 0; kk < 64; ++kk) {
            float4 w = *(const float4*)(Wp1 + (size_t)(kb + kk) * NP + c4 * 4);
            float4 f = *(const float4*)(sT + kk * 20 + mq * 4);  // broadcast read
            acc[0][0] += f.x * w.x; acc[0][1] += f.x * w.y; acc[0][2] += f.x * w.z; acc[0][3] += f.x * w.w;
            acc[1][0] += f.y * w.x; acc[1][1] += f.y * w.y; acc[1][2] += f.y * w.z; acc[1][3] += f.y * w.w;
            acc[2][0] += f.z * w.x; acc[2][1] += f.z * w.y; acc[2][2] += f.z * w.z; acc[2][3] += f.z * w.w;
            acc[3][0] += f.w * w.x; acc[3][1] += f.w * w.y; acc[3][2] += f.w * w.z; acc[3][3] += f.w * w.w;
        }
        __syncthreads();
    }
    float* p = part + (size_t)blockIdx.x * (NB * NP);
#pragma unroll
    for (int i = 0; i < 4; ++i) {
        float4 o = make_float4(acc[i][0], acc[i][1], acc[i][2], acc[i][3]);
        *(float4*)(p + (mq * 4 + i) * NP + c4 * 4) = o;
    }
}

__global__ __launch_bounds__(256) void k_reduce(const float* __restrict__ part,
                                                const float* __restrict__ bp1,
                                                float* __restrict__ hid) {
    int o = blockIdx.x * 256 + threadIdx.x;   // 0..8191
    float s = bp1[o & (NP - 1)];
#pragma unroll 10
    for (int ch = 0; ch < KCH; ++ch) s += part[(size_t)ch * (NB * NP) + o];
    hid[o] = fmaxf(s, 0.f);
}

// ---------------- out[16][16] = hid[16][512] @ Wp2 + bp2 ----------------

__global__ __launch_bounds__(256) void k_gemm2(const float* __restrict__ hid,
                                               const float* __restrict__ Wp2,
                                               const float* __restrict__ bp2,
                                               float* __restrict__ out) {
    int t = threadIdx.x;
    int m = t >> 4, a = t & 15;
    int ks = blockIdx.x * 64;
    float acc = (blockIdx.x == 0) ? bp2[a] : 0.f;
#pragma unroll
    for (int k = 0; k < 64; k += 4) {
        float4 hv = *(const float4*)(hid + m * NP + ks + k);
        acc += hv.x * Wp2[(ks + k + 0) * NA + a];
        acc += hv.y * Wp2[(ks + k + 1) * NA + a];
        acc += hv.z * Wp2[(ks + k + 2) * NA + a];
        acc += hv.w * Wp2[(ks + k + 3) * NA + a];
    }
    atomicAdd(out + m * NA + a, acc);
}

// ---------------- launch ----------------

static inline size_t align256(size_t x) { return (x + 255) & ~(size_t)255; }

extern "C" void kernel_launch(void* const* d_in, const int* in_sizes, int n_in,
                              void* d_out, int out_size, void* d_ws, size_t ws_size,
                              hipStream_t stream) {
    const float* feat = (const float*)d_in[0];
    const int*   ei   = (const int*)d_in[1];      // int32 on device (JAX x64 disabled)
    const float* W1   = (const float*)d_in[2];
    const float* b1   = (const float*)d_in[3];
    const float* W2   = (const float*)d_in[4];
    const float* b2   = (const float*)d_in[5];
    const float* Wp1  = (const float*)d_in[6];
    const float* bp1  = (const float*)d_in[7];
    const float* Wp2  = (const float*)d_in[8];
    const float* bp2  = (const float*)d_in[9];
    float* out = (float*)d_out;

    char* w = (char*)d_ws;
    size_t off = 0;
    int*   deg    = (int*)(w + off);   off = align256(off + NN * 4);
    int*   offs   = (int*)(w + off);   off = align256(off + (NN + 1) * 4);
    int*   cursor = (int*)(w + off);   off = align256(off + NN * 4);
    float* dinv   = (float*)(w + off); off = align256(off + NN * 4);
    int2*  pack   = (int2*)(w + off);  off = align256(off + (size_t)NE * 8);
    float* bufA   = (float*)(w + off); off = align256(off + (size_t)NB * NN * NH * 4); // xw1, later h2
    float* bufB   = (float*)(w + off); off = align256(off + (size_t)NB * NN * NH * 4); // h1, later partials
    float* hid    = (float*)(w + off); off = align256(off + (size_t)NB * NP * 4);
    (void)ws_size; (void)n_in; (void)in_sizes; (void)out_size;

    hipMemsetAsync(deg, 0, NN * 4, stream);
    hipMemsetAsync(out, 0, NB * NA * 4, stream);

    k_hist<<<(NE + 255) / 256, 256, 0, stream>>>(ei, deg);
    k_scan<<<1, 1024, 0, stream>>>(deg, offs, cursor, dinv);
    k_fill<<<(NE + 255) / 256, 256, 0, stream>>>(ei, dinv, cursor, pack);

    k_xform1<<<(NB * NN) / 32, 256, 0, stream>>>(feat, W1, bufA);      // bufA = xw1
    k_agg1<<<NB * (NN / 4), 256, 0, stream>>>(bufA, offs, dinv, pack, b1, bufB);   // bufB = h1
    k_agg2<<<NB * (NN / 4), 256, 0, stream>>>(bufB, offs, dinv, pack, W2, b2, bufA); // bufA = h2 (= flat)

    k_gemm1<<<KCH, 512, 0, stream>>>(bufA, Wp1, bufB);                 // bufB = partials (8 MB)
    k_reduce<<<(NB * NP) / 256, 256, 0, stream>>>(bufB, bp1, hid);
    k_gemm2<<<NP / 64, 256, 0, stream>>>(hid, Wp2, bp2, out);
}

// Round 3
// 673.210 us; speedup vs baseline: 1.0600x; 1.0600x over previous
//
#include <hip/hip_runtime.h>
#include <hip/hip_bf16.h>

// Problem constants (fixed by the reference):
#define NB 16        // batch
#define NN 5000      // nodes
#define NF 64        // in features
#define NH 32        // hidden
#define NE 160000    // edges (without self loops)
#define NP 512       // policy hidden
#define NA 16        // actions
#define KCH 500      // K-chunks for big GEMM
#define KLEN 320     // K per chunk (500*320 = 160000)

// ---------------- CSR build ----------------
// edge_index is int32 on device (JAX default x64-disabled; harness passes int*).

__global__ __launch_bounds__(256) void k_hist(const int* __restrict__ ei,
                                              int* __restrict__ deg) {
    int e = blockIdx.x * 256 + threadIdx.x;
    if (e < NE) atomicAdd(&deg[ei[NE + e]], 1);
}

__global__ __launch_bounds__(1024) void k_scan(const int* __restrict__ deg,
                                               int* __restrict__ offs,
                                               int* __restrict__ cursor,
                                               float* __restrict__ dinv) {
    __shared__ int sm[1024];
    int t = threadIdx.x;
    int v[5]; int sum = 0;
    int base = t * 5;
#pragma unroll
    for (int i = 0; i < 5; ++i) {
        int idx = base + i;
        int d = (idx < NN) ? deg[idx] : 0;
        v[i] = d; sum += d;
    }
    sm[t] = sum; __syncthreads();
    for (int off = 1; off < 1024; off <<= 1) {
        int x = (t >= off) ? sm[t - off] : 0;
        __syncthreads();
        sm[t] += x;
        __syncthreads();
    }
    int excl = (t == 0) ? 0 : sm[t - 1];
#pragma unroll
    for (int i = 0; i < 5; ++i) {
        int idx = base + i;
        if (idx < NN) {
            offs[idx] = excl; cursor[idx] = excl;
            dinv[idx] = 1.0f / sqrtf((float)(v[i] + 1));  // +1 self loop
            excl += v[i];
        }
    }
    if (t == 1023) offs[NN] = sm[1023];
}

__global__ __launch_bounds__(256) void k_fill(const int* __restrict__ ei,
                                              const float* __restrict__ dinv,
                                              int* __restrict__ cursor,
                                              int2* __restrict__ pack) {
    int e = blockIdx.x * 256 + threadIdx.x;
    if (e < NE) {
        int s = ei[e];
        int d = ei[NE + e];
        float nrm = dinv[s] * dinv[d];
        int pos = atomicAdd(&cursor[d], 1);
        pack[pos] = make_int2(s, __float_as_int(nrm));
    }
}

// ---------------- Layer 1 transform: xw[b][n][h] = feat[b][n][:] @ W1 ----------------

__global__ __launch_bounds__(256) void k_xform1(const float* __restrict__ feat,
                                                const float* __restrict__ W1,
                                                float* __restrict__ xw) {
    __shared__ float w1s[NF * NH];   // 8 KB, same layout as global
    int t = threadIdx.x;
    for (int i = t; i < NF * NH; i += 256) w1s[i] = W1[i];
    __syncthreads();
    int h = t & 31;
    int rg = t >> 5;                         // 0..7
    int r0 = blockIdx.x * 32 + rg * 4;       // 4 rows per thread, rows = b*NN+n
    const float4* f4 = (const float4*)feat;  // row r -> f4[r*16 + q]
    float acc0 = 0.f, acc1 = 0.f, acc2 = 0.f, acc3 = 0.f;
#pragma unroll
    for (int q = 0; q < 16; ++q) {
        float4 a0 = f4[(size_t)(r0 + 0) * 16 + q];
        float4 a1 = f4[(size_t)(r0 + 1) * 16 + q];
        float4 a2 = f4[(size_t)(r0 + 2) * 16 + q];
        float4 a3 = f4[(size_t)(r0 + 3) * 16 + q];
        float w0 = w1s[(q * 4 + 0) * NH + h];
        float w1_ = w1s[(q * 4 + 1) * NH + h];
        float w2_ = w1s[(q * 4 + 2) * NH + h];
        float w3_ = w1s[(q * 4 + 3) * NH + h];
        acc0 += a0.x * w0; acc0 += a0.y * w1_; acc0 += a0.z * w2_; acc0 += a0.w * w3_;
        acc1 += a1.x * w0; acc1 += a1.y * w1_; acc1 += a1.z * w2_; acc1 += a1.w * w3_;
        acc2 += a2.x * w0; acc2 += a2.y * w1_; acc2 += a2.z * w2_; acc2 += a2.w * w3_;
        acc3 += a3.x * w0; acc3 += a3.y * w1_; acc3 += a3.z * w2_; acc3 += a3.w * w3_;
    }
    xw[(size_t)(r0 + 0) * NH + h] = acc0;
    xw[(size_t)(r0 + 1) * NH + h] = acc1;
    xw[(size_t)(r0 + 2) * NH + h] = acc2;
    xw[(size_t)(r0 + 3) * NH + h] = acc3;
}

// ---------------- Aggregation helpers ----------------
// grid 20000: xcd-swizzled (batch, node-group-of-4); wave per (b,n); lane: h=lane&31, half=lane>>5

__device__ __forceinline__ void agg_decode(int bid, int tid, int& b, int& n,
                                           int& hp, int& half) {
    int xcd = bid & 7;
    int g = bid >> 3;                 // 0..2499
    int hi = (g >= 1250) ? 1 : 0;
    b = xcd * 2 + hi;
    int ng = g - hi * 1250;           // 0..1249
    int w = tid >> 6;                 // 0..3
    n = ng * 4 + w;
    int lane = tid & 63;
    hp = lane & 31;
    half = lane >> 5;
}

// edge loop with pack-prefetch: issue next pack load before gather's waitcnt
__device__ __forceinline__ float edge_agg(const int2* __restrict__ pack,
                                          const float* __restrict__ inb,
                                          int s0, int s1, int half, int hp) {
    float acc = 0.f;
    int e = s0 + half;
    bool have = e < s1;
    int2 p = have ? pack[e] : make_int2(0, 0);
    while (have) {
        int2 cur = p;
        int en = e + 2;
        bool hn = en < s1;
        if (hn) p = pack[en];
        acc += __int_as_float(cur.y) * inb[(size_t)cur.x * NH + hp];
        e = en; have = hn;
    }
    return acc;
}

__global__ __launch_bounds__(256) void k_agg1(const float* __restrict__ xw,
                                              const int* __restrict__ offs,
                                              const float* __restrict__ dinv,
                                              const int2* __restrict__ pack,
                                              const float* __restrict__ b1,
                                              float* __restrict__ out) {
    int b, n, hp, half;
    agg_decode(blockIdx.x, threadIdx.x, b, n, hp, half);
    const float* inb = xw + (size_t)b * (NN * NH);
    int s0 = offs[n], s1 = offs[n + 1];
    float acc = edge_agg(pack, inb, s0, s1, half, hp);
    acc += __shfl_xor(acc, 32);
    float di = dinv[n];
    float v = acc + di * di * inb[(size_t)n * NH + hp] + b1[hp];
    v = fmaxf(v, 0.f);
    if ((threadIdx.x & 63) < 32)
        out[(size_t)b * (NN * NH) + (size_t)n * NH + hp] = v;
}

// ---------------- Aggregation (layer 2) fused with @W2 + b2 + relu ----------------
// agg(h1 @ W2) == agg(h1) @ W2  (aggregation is linear over the feature dim)

__global__ __launch_bounds__(256) void k_agg2(const float* __restrict__ h1,
                                              const int* __restrict__ offs,
                                              const float* __restrict__ dinv,
                                              const int2* __restrict__ pack,
                                              const float* __restrict__ W2,
                                              const float* __restrict__ b2,
                                              float* __restrict__ h2) {
    int b, n, hp, half;
    agg_decode(blockIdx.x, threadIdx.x, b, n, hp, half);
    // W2 column hp into registers (L1-hot, 4 KB total)
    float w2c[NH];
#pragma unroll
    for (int kh = 0; kh < NH; ++kh) w2c[kh] = W2[kh * NH + hp];
    const float* inb = h1 + (size_t)b * (NN * NH);
    int s0 = offs[n], s1 = offs[n + 1];
    float acc = edge_agg(pack, inb, s0, s1, half, hp);
    acc += __shfl_xor(acc, 32);
    float di = dinv[n];
    float aggv = acc + di * di * inb[(size_t)n * NH + hp];   // pre-transform agg, valid on all lanes
    float o = b2[hp];
#pragma unroll
    for (int kh = 0; kh < NH; ++kh) {
        float av = __uint_as_float(__builtin_amdgcn_readlane(__float_as_uint(aggv), kh));
        o += av * w2c[kh];
    }
    o = fmaxf(o, 0.f);
    if ((threadIdx.x & 63) < 32)
        h2[(size_t)b * (NN * NH) + (size_t)n * NH + hp] = o;
}

// ---------------- Big GEMM: partials[ch][16][512] = flat[16][Kch] @ Wp1[Kch][512] ----------------
// 500 blocks (~2/CU), 512 threads; __launch_bounds__(512,4) -> 2 blocks/CU resident.

__global__ __launch_bounds__(512, 4) void k_gemm1(const float* __restrict__ flat,
                                                  const float* __restrict__ Wp1,
                                                  float* __restrict__ part) {
    __shared__ __align__(16) float sT[64 * 20];  // [kk][m] with pad 20 (16B-aligned rows)
    int t = threadIdx.x;
    int c4 = t & 127;          // cols 4*c4 .. 4*c4+3
    int mq = t >> 7;           // 0..3 -> rows mq*4..+4
    int lane = t & 63;
    int r2 = t >> 6;           // 0..7 -> stages rows r2*2, r2*2+1
    int k0 = blockIdx.x * KLEN;
    float acc[4][4] = {{0.f}};
    for (int sub = 0; sub < KLEN / 64; ++sub) {   // 5 subs
        int kb = k0 + sub * 64;
#pragma unroll
        for (int i = 0; i < 2; ++i) {
            int m = r2 * 2 + i;
            sT[lane * 20 + m] = flat[(size_t)m * (NN * NH) + kb + lane];
        }
        __syncthreads();
#pragma unroll 8
        for (int kk = 0; kk < 64; ++kk) {
            float4 w = *(const float4*)(Wp1 + (size_t)(kb + kk) * NP + c4 * 4);
            float4 f = *(const float4*)(sT + kk * 20 + mq * 4);  // broadcast read
            acc[0][0] += f.x * w.x; acc[0][1] += f.x * w.y; acc[0][2] += f.x * w.z; acc[0][3] += f.x * w.w;
            acc[1][0] += f.y * w.x; acc[1][1] += f.y * w.y; acc[1][2] += f.y * w.z; acc[1][3] += f.y * w.w;
            acc[2][0] += f.z * w.x; acc[2][1] += f.z * w.y; acc[2][2] += f.z * w.z; acc[2][3] += f.z * w.w;
            acc[3][0] += f.w * w.x; acc[3][1] += f.w * w.y; acc[3][2] += f.w * w.z; acc[3][3] += f.w * w.w;
        }
        __syncthreads();
    }
    float* p = part + (size_t)blockIdx.x * (NB * NP);
#pragma unroll
    for (int i = 0; i < 4; ++i) {
        float4 o = make_float4(acc[i][0], acc[i][1], acc[i][2], acc[i][3]);
        *(float4*)(p + (mq * 4 + i) * NP + c4 * 4) = o;
    }
}

// reduce partials over chunk quarters; hid pre-zeroed; bias+relu applied in gemm2
__global__ __launch_bounds__(256) void k_reduce(const float* __restrict__ part,
                                                float* __restrict__ hid) {
    int o = blockIdx.x * 256 + threadIdx.x;       // 0..8191
    int c0 = blockIdx.y * (KCH / 4);              // 4 groups of 125 chunks
    float s = 0.f;
#pragma unroll 5
    for (int ch = c0; ch < c0 + KCH / 4; ++ch) s += part[(size_t)ch * (NB * NP) + o];
    atomicAdd(&hid[o], s);
}

// ---------------- out[16][16] = relu(hid + bp1) @ Wp2 + bp2 ----------------

__global__ __launch_bounds__(256) void k_gemm2(const float* __restrict__ hid,
                                               const float* __restrict__ bp1,
                                               const float* __restrict__ Wp2,
                                               const float* __restrict__ bp2,
                                               float* __restrict__ out) {
    int t = threadIdx.x;
    int m = t >> 4, a = t & 15;
    int ks = blockIdx.x * 64;
    float acc = (blockIdx.x == 0) ? bp2[a] : 0.f;
#pragma unroll
    for (int k = 0; k < 64; k += 4) {
        float4 hv = *(const float4*)(hid + m * NP + ks + k);
        float4 bv = *(const float4*)(bp1 + ks + k);
        float h0 = fmaxf(hv.x + bv.x, 0.f);
        float h1 = fmaxf(hv.y + bv.y, 0.f);
        float h2 = fmaxf(hv.z + bv.z, 0.f);
        float h3 = fmaxf(hv.w + bv.w, 0.f);
        acc += h0 * Wp2[(ks + k + 0) * NA + a];
        acc += h1 * Wp2[(ks + k + 1) * NA + a];
        acc += h2 * Wp2[(ks + k + 2) * NA + a];
        acc += h3 * Wp2[(ks + k + 3) * NA + a];
    }
    atomicAdd(out + m * NA + a, acc);
}

// ---------------- launch ----------------

static inline size_t align256(size_t x) { return (x + 255) & ~(size_t)255; }

extern "C" void kernel_launch(void* const* d_in, const int* in_sizes, int n_in,
                              void* d_out, int out_size, void* d_ws, size_t ws_size,
                              hipStream_t stream) {
    const float* feat = (const float*)d_in[0];
    const int*   ei   = (const int*)d_in[1];      // int32 on device (JAX x64 disabled)
    const float* W1   = (const float*)d_in[2];
    const float* b1   = (const float*)d_in[3];
    const float* W2   = (const float*)d_in[4];
    const float* b2   = (const float*)d_in[5];
    const float* Wp1  = (const float*)d_in[6];
    const float* bp1  = (const float*)d_in[7];
    const float* Wp2  = (const float*)d_in[8];
    const float* bp2  = (const float*)d_in[9];
    float* out = (float*)d_out;

    char* w = (char*)d_ws;
    size_t off = 0;
    int*   deg    = (int*)(w + off);   off = align256(off + NN * 4);
    int*   offs   = (int*)(w + off);   off = align256(off + (NN + 1) * 4);
    int*   cursor = (int*)(w + off);   off = align256(off + NN * 4);
    float* dinv   = (float*)(w + off); off = align256(off + NN * 4);
    int2*  pack   = (int2*)(w + off);  off = align256(off + (size_t)NE * 8);
    float* bufA   = (float*)(w + off); off = align256(off + (size_t)NB * NN * NH * 4); // xw1, later h2
    float* bufB   = (float*)(w + off); off = align256(off + (size_t)NB * NN * NH * 4); // h1
    float* part   = (float*)(w + off); off = align256(off + (size_t)KCH * NB * NP * 4); // 16.4 MB
    float* hid    = (float*)(w + off); off = align256(off + (size_t)NB * NP * 4);
    (void)ws_size; (void)n_in; (void)in_sizes; (void)out_size;

    hipMemsetAsync(deg, 0, NN * 4, stream);
    hipMemsetAsync(hid, 0, NB * NP * 4, stream);
    hipMemsetAsync(out, 0, NB * NA * 4, stream);

    k_hist<<<(NE + 255) / 256, 256, 0, stream>>>(ei, deg);
    k_scan<<<1, 1024, 0, stream>>>(deg, offs, cursor, dinv);
    k_fill<<<(NE + 255) / 256, 256, 0, stream>>>(ei, dinv, cursor, pack);

    k_xform1<<<(NB * NN) / 32, 256, 0, stream>>>(feat, W1, bufA);      // bufA = xw1
    k_agg1<<<NB * (NN / 4), 256, 0, stream>>>(bufA, offs, dinv, pack, b1, bufB);   // bufB = h1
    k_agg2<<<NB * (NN / 4), 256, 0, stream>>>(bufB, offs, dinv, pack, W2, b2, bufA); // bufA = h2 (= flat)

    k_gemm1<<<KCH, 512, 0, stream>>>(bufA, Wp1, part);                 // part = partials (16.4 MB)
    k_reduce<<<dim3(NB * NP / 256, 4), 256, 0, stream>>>(part, hid);
    k_gemm2<<<NP / 64, 256, 0, stream>>>(hid, bp1, Wp2, bp2, out);
}

// Round 4
// 633.552 us; speedup vs baseline: 1.1263x; 1.0626x over previous
//
#include <hip/hip_runtime.h>
#include <hip/hip_bf16.h>

// Problem constants (fixed by the reference):
#define NB 16        // batch
#define NN 5000      // nodes
#define NF 64        // in features
#define NH 32        // hidden
#define NE 160000    // edges (without self loops)
#define NP 512       // policy hidden
#define NA 16        // actions
#define KCH 500      // K-chunks for big GEMM
#define KLEN 320     // K per chunk (500*320 = 160000)

// ---------------- CSR build ----------------
// edge_index is int32 on device (JAX default x64-disabled; harness passes int*).

__global__ __launch_bounds__(256) void k_hist(const int* __restrict__ ei,
                                              int* __restrict__ deg) {
    int e = blockIdx.x * 256 + threadIdx.x;
    if (e < NE) atomicAdd(&deg[ei[NE + e]], 1);
}

__global__ __launch_bounds__(1024) void k_scan(const int* __restrict__ deg,
                                               int* __restrict__ offs,
                                               int* __restrict__ cursor,
                                               float* __restrict__ dinv) {
    __shared__ int sm[1024];
    int t = threadIdx.x;
    int v[5]; int sum = 0;
    int base = t * 5;
#pragma unroll
    for (int i = 0; i < 5; ++i) {
        int idx = base + i;
        int d = (idx < NN) ? deg[idx] : 0;
        v[i] = d; sum += d;
    }
    sm[t] = sum; __syncthreads();
    for (int off = 1; off < 1024; off <<= 1) {
        int x = (t >= off) ? sm[t - off] : 0;
        __syncthreads();
        sm[t] += x;
        __syncthreads();
    }
    int excl = (t == 0) ? 0 : sm[t - 1];
#pragma unroll
    for (int i = 0; i < 5; ++i) {
        int idx = base + i;
        if (idx < NN) {
            offs[idx] = excl; cursor[idx] = excl;
            dinv[idx] = 1.0f / sqrtf((float)(v[i] + 1));  // +1 self loop
            excl += v[i];
        }
    }
    if (t == 1023) offs[NN] = sm[1023];
}

__global__ __launch_bounds__(256) void k_fill(const int* __restrict__ ei,
                                              const float* __restrict__ dinv,
                                              int* __restrict__ cursor,
                                              int2* __restrict__ pack) {
    int e = blockIdx.x * 256 + threadIdx.x;
    if (e < NE) {
        int s = ei[e];
        int d = ei[NE + e];
        float nrm = dinv[s] * dinv[d];
        int pos = atomicAdd(&cursor[d], 1);
        pack[pos] = make_int2(s, __float_as_int(nrm));
    }
}

// ---------------- Layer 1 transform: xw[b][n][h] = feat[b][n][:] @ W1 ----------------

__global__ __launch_bounds__(256) void k_xform1(const float* __restrict__ feat,
                                                const float* __restrict__ W1,
                                                float* __restrict__ xw) {
    __shared__ float w1s[NF * NH];   // 8 KB, same layout as global
    int t = threadIdx.x;
    for (int i = t; i < NF * NH; i += 256) w1s[i] = W1[i];
    __syncthreads();
    int h = t & 31;
    int rg = t >> 5;                         // 0..7
    int r0 = blockIdx.x * 32 + rg * 4;       // 4 rows per thread, rows = b*NN+n
    const float4* f4 = (const float4*)feat;  // row r -> f4[r*16 + q]
    float acc0 = 0.f, acc1 = 0.f, acc2 = 0.f, acc3 = 0.f;
#pragma unroll
    for (int q = 0; q < 16; ++q) {
        float4 a0 = f4[(size_t)(r0 + 0) * 16 + q];
        float4 a1 = f4[(size_t)(r0 + 1) * 16 + q];
        float4 a2 = f4[(size_t)(r0 + 2) * 16 + q];
        float4 a3 = f4[(size_t)(r0 + 3) * 16 + q];
        float w0 = w1s[(q * 4 + 0) * NH + h];
        float w1_ = w1s[(q * 4 + 1) * NH + h];
        float w2_ = w1s[(q * 4 + 2) * NH + h];
        float w3_ = w1s[(q * 4 + 3) * NH + h];
        acc0 += a0.x * w0; acc0 += a0.y * w1_; acc0 += a0.z * w2_; acc0 += a0.w * w3_;
        acc1 += a1.x * w0; acc1 += a1.y * w1_; acc1 += a1.z * w2_; acc1 += a1.w * w3_;
        acc2 += a2.x * w0; acc2 += a2.y * w1_; acc2 += a2.z * w2_; acc2 += a2.w * w3_;
        acc3 += a3.x * w0; acc3 += a3.y * w1_; acc3 += a3.z * w2_; acc3 += a3.w * w3_;
    }
    xw[(size_t)(r0 + 0) * NH + h] = acc0;
    xw[(size_t)(r0 + 1) * NH + h] = acc1;
    xw[(size_t)(r0 + 2) * NH + h] = acc2;
    xw[(size_t)(r0 + 3) * NH + h] = acc3;
}

// ---------------- Aggregation helpers ----------------
// grid 20000: xcd-swizzled (batch, node-group-of-4); wave per (b,n); lane: h=lane&31, half=lane>>5

__device__ __forceinline__ void agg_decode(int bid, int tid, int& b, int& n,
                                           int& hp, int& half) {
    int xcd = bid & 7;
    int g = bid >> 3;                 // 0..2499
    int hi = (g >= 1250) ? 1 : 0;
    b = xcd * 2 + hi;
    int ng = g - hi * 1250;           // 0..1249
    int w = tid >> 6;                 // 0..3
    n = ng * 4 + w;
    int lane = tid & 63;
    hp = lane & 31;
    half = lane >> 5;
}

// contiguous per-half edge range [lo,hi); 4-wide software-pipelined:
// next 4 pack loads issued before current 4 gathers are consumed -> 8 loads in flight
__device__ __forceinline__ float edge_agg(const int2* __restrict__ pack,
                                          const float* __restrict__ inb,
                                          int lo, int hi, int hp) {
    float acc = 0.f;
    int e = lo;
    int2 p0, p1, p2, p3;
    if (e + 3 < hi) { p0 = pack[e]; p1 = pack[e + 1]; p2 = pack[e + 2]; p3 = pack[e + 3]; }
    while (e + 3 < hi) {
        int2 c0 = p0, c1 = p1, c2 = p2, c3 = p3;
        int en = e + 4;
        if (en + 3 < hi) { p0 = pack[en]; p1 = pack[en + 1]; p2 = pack[en + 2]; p3 = pack[en + 3]; }
        float v0 = inb[(size_t)c0.x * NH + hp];
        float v1 = inb[(size_t)c1.x * NH + hp];
        float v2 = inb[(size_t)c2.x * NH + hp];
        float v3 = inb[(size_t)c3.x * NH + hp];
        acc += __int_as_float(c0.y) * v0;
        acc += __int_as_float(c1.y) * v1;
        acc += __int_as_float(c2.y) * v2;
        acc += __int_as_float(c3.y) * v3;
        e = en;
    }
    for (; e < hi; ++e) {
        int2 p = pack[e];
        acc += __int_as_float(p.y) * inb[(size_t)p.x * NH + hp];
    }
    return acc;
}

__device__ __forceinline__ void half_range(int s0, int s1, int half, int& lo, int& hi) {
    int cnt = s1 - s0;
    int c0 = (cnt + 1) >> 1;          // first half gets the extra on odd counts
    lo = s0 + (half ? c0 : 0);
    hi = half ? s1 : (s0 + c0);
}

__global__ __launch_bounds__(256) void k_agg1(const float* __restrict__ xw,
                                              const int* __restrict__ offs,
                                              const float* __restrict__ dinv,
                                              const int2* __restrict__ pack,
                                              const float* __restrict__ b1,
                                              float* __restrict__ out) {
    int b, n, hp, half;
    agg_decode(blockIdx.x, threadIdx.x, b, n, hp, half);
    const float* inb = xw + (size_t)b * (NN * NH);
    int s0 = offs[n], s1 = offs[n + 1];
    int lo, hi; half_range(s0, s1, half, lo, hi);
    float acc = edge_agg(pack, inb, lo, hi, hp);
    acc += __shfl_xor(acc, 32);
    float di = dinv[n];
    float v = acc + di * di * inb[(size_t)n * NH + hp] + b1[hp];
    v = fmaxf(v, 0.f);
    if ((threadIdx.x & 63) < 32)
        out[(size_t)b * (NN * NH) + (size_t)n * NH + hp] = v;
}

// ---------------- Aggregation (layer 2) fused with @W2 + b2 + relu ----------------
// agg(h1 @ W2) == agg(h1) @ W2  (aggregation is linear over the feature dim)

__global__ __launch_bounds__(256) void k_agg2(const float* __restrict__ h1,
                                              const int* __restrict__ offs,
                                              const float* __restrict__ dinv,
                                              const int2* __restrict__ pack,
                                              const float* __restrict__ W2,
                                              const float* __restrict__ b2,
                                              float* __restrict__ h2) {
    int b, n, hp, half;
    agg_decode(blockIdx.x, threadIdx.x, b, n, hp, half);
    // W2 column hp into registers (L1-hot, 4 KB total)
    float w2c[NH];
#pragma unroll
    for (int kh = 0; kh < NH; ++kh) w2c[kh] = W2[kh * NH + hp];
    const float* inb = h1 + (size_t)b * (NN * NH);
    int s0 = offs[n], s1 = offs[n + 1];
    int lo, hi; half_range(s0, s1, half, lo, hi);
    float acc = edge_agg(pack, inb, lo, hi, hp);
    acc += __shfl_xor(acc, 32);
    float di = dinv[n];
    float aggv = acc + di * di * inb[(size_t)n * NH + hp];   // pre-transform agg, valid on all lanes
    float o = b2[hp];
#pragma unroll
    for (int kh = 0; kh < NH; ++kh) {
        float av = __uint_as_float(__builtin_amdgcn_readlane(__float_as_uint(aggv), kh));
        o += av * w2c[kh];
    }
    o = fmaxf(o, 0.f);
    if ((threadIdx.x & 63) < 32)
        h2[(size_t)b * (NN * NH) + (size_t)n * NH + hp] = o;
}

// ---------------- Big GEMM: partials[ch][16][512] = flat[16][Kch] @ Wp1[Kch][512] ----------------
// 500 blocks (~2/CU), 512 threads; __launch_bounds__(512,4) -> 2 blocks/CU resident.

__global__ __launch_bounds__(512, 4) void k_gemm1(const float* __restrict__ flat,
                                                  const float* __restrict__ Wp1,
                                                  float* __restrict__ part) {
    __shared__ __align__(16) float sT[64 * 20];  // [kk][m] with pad 20 (16B-aligned rows)
    int t = threadIdx.x;
    int c4 = t & 127;          // cols 4*c4 .. 4*c4+3
    int mq = t >> 7;           // 0..3 -> rows mq*4..+4
    int lane = t & 63;
    int r2 = t >> 6;           // 0..7 -> stages rows r2*2, r2*2+1
    int k0 = blockIdx.x * KLEN;
    float acc[4][4] = {{0.f}};
    for (int sub = 0; sub < KLEN / 64; ++sub) {   // 5 subs
        int kb = k0 + sub * 64;
#pragma unroll
        for (int i = 0; i < 2; ++i) {
            int m = r2 * 2 + i;
            sT[lane * 20 + m] = flat[(size_t)m * (NN * NH) + kb + lane];
        }
        __syncthreads();
#pragma unroll 8
        for (int kk = 0; kk < 64; ++kk) {
            float4 w = *(const float4*)(Wp1 + (size_t)(kb + kk) * NP + c4 * 4);
            float4 f = *(const float4*)(sT + kk * 20 + mq * 4);  // broadcast read
            acc[0][0] += f.x * w.x; acc[0][1] += f.x * w.y; acc[0][2] += f.x * w.z; acc[0][3] += f.x * w.w;
            acc[1][0] += f.y * w.x; acc[1][1] += f.y * w.y; acc[1][2] += f.y * w.z; acc[1][3] += f.y * w.w;
            acc[2][0] += f.z * w.x; acc[2][1] += f.z * w.y; acc[2][2] += f.z * w.z; acc[2][3] += f.z * w.w;
            acc[3][0] += f.w * w.x; acc[3][1] += f.w * w.y; acc[3][2] += f.w * w.z; acc[3][3] += f.w * w.w;
        }
        __syncthreads();
    }
    float* p = part + (size_t)blockIdx.x * (NB * NP);
#pragma unroll
    for (int i = 0; i < 4; ++i) {
        float4 o = make_float4(acc[i][0], acc[i][1], acc[i][2], acc[i][3]);
        *(float4*)(p + (mq * 4 + i) * NP + c4 * 4) = o;
    }
}

// reduce partials over chunk quarters; hid pre-zeroed; bias+relu applied in gemm2
__global__ __launch_bounds__(256) void k_reduce(const float* __restrict__ part,
                                                float* __restrict__ hid) {
    int o = blockIdx.x * 256 + threadIdx.x;       // 0..8191
    int c0 = blockIdx.y * (KCH / 4);              // 4 groups of 125 chunks
    float s = 0.f;
#pragma unroll 5
    for (int ch = c0; ch < c0 + KCH / 4; ++ch) s += part[(size_t)ch * (NB * NP) + o];
    atomicAdd(&hid[o], s);
}

// ---------------- out[16][16] = relu(hid + bp1) @ Wp2 + bp2 ----------------

__global__ __launch_bounds__(256) void k_gemm2(const float* __restrict__ hid,
                                               const float* __restrict__ bp1,
                                               const float* __restrict__ Wp2,
                                               const float* __restrict__ bp2,
                                               float* __restrict__ out) {
    int t = threadIdx.x;
    int m = t >> 4, a = t & 15;
    int ks = blockIdx.x * 64;
    float acc = (blockIdx.x == 0) ? bp2[a] : 0.f;
#pragma unroll
    for (int k = 0; k < 64; k += 4) {
        float4 hv = *(const float4*)(hid + m * NP + ks + k);
        float4 bv = *(const float4*)(bp1 + ks + k);
        float h0 = fmaxf(hv.x + bv.x, 0.f);
        float h1 = fmaxf(hv.y + bv.y, 0.f);
        float h2 = fmaxf(hv.z + bv.z, 0.f);
        float h3 = fmaxf(hv.w + bv.w, 0.f);
        acc += h0 * Wp2[(ks + k + 0) * NA + a];
        acc += h1 * Wp2[(ks + k + 1) * NA + a];
        acc += h2 * Wp2[(ks + k + 2) * NA + a];
        acc += h3 * Wp2[(ks + k + 3) * NA + a];
    }
    atomicAdd(out + m * NA + a, acc);
}

// ---------------- launch ----------------

static inline size_t align256(size_t x) { return (x + 255) & ~(size_t)255; }

extern "C" void kernel_launch(void* const* d_in, const int* in_sizes, int n_in,
                              void* d_out, int out_size, void* d_ws, size_t ws_size,
                              hipStream_t stream) {
    const float* feat = (const float*)d_in[0];
    const int*   ei   = (const int*)d_in[1];      // int32 on device (JAX x64 disabled)
    const float* W1   = (const float*)d_in[2];
    const float* b1   = (const float*)d_in[3];
    const float* W2   = (const float*)d_in[4];
    const float* b2   = (const float*)d_in[5];
    const float* Wp1  = (const float*)d_in[6];
    const float* bp1  = (const float*)d_in[7];
    const float* Wp2  = (const float*)d_in[8];
    const float* bp2  = (const float*)d_in[9];
    float* out = (float*)d_out;

    char* w = (char*)d_ws;
    size_t off = 0;
    int*   deg    = (int*)(w + off);   off = align256(off + NN * 4);
    int*   offs   = (int*)(w + off);   off = align256(off + (NN + 1) * 4);
    int*   cursor = (int*)(w + off);   off = align256(off + NN * 4);
    float* dinv   = (float*)(w + off); off = align256(off + NN * 4);
    int2*  pack   = (int2*)(w + off);  off = align256(off + (size_t)NE * 8);
    float* bufA   = (float*)(w + off); off = align256(off + (size_t)NB * NN * NH * 4); // xw1, later h2
    float* bufB   = (float*)(w + off); off = align256(off + (size_t)NB * NN * NH * 4); // h1
    float* part   = (float*)(w + off); off = align256(off + (size_t)KCH * NB * NP * 4); // 16.4 MB
    float* hid    = (float*)(w + off); off = align256(off + (size_t)NB * NP * 4);
    (void)ws_size; (void)n_in; (void)in_sizes; (void)out_size;

    hipMemsetAsync(deg, 0, NN * 4, stream);
    hipMemsetAsync(hid, 0, NB * NP * 4, stream);
    hipMemsetAsync(out, 0, NB * NA * 4, stream);

    k_hist<<<(NE + 255) / 256, 256, 0, stream>>>(ei, deg);
    k_scan<<<1, 1024, 0, stream>>>(deg, offs, cursor, dinv);
    k_fill<<<(NE + 255) / 256, 256, 0, stream>>>(ei, dinv, cursor, pack);

    k_xform1<<<(NB * NN) / 32, 256, 0, stream>>>(feat, W1, bufA);      // bufA = xw1
    k_agg1<<<NB * (NN / 4), 256, 0, stream>>>(bufA, offs, dinv, pack, b1, bufB);   // bufB = h1
    k_agg2<<<NB * (NN / 4), 256, 0, stream>>>(bufB, offs, dinv, pack, W2, b2, bufA); // bufA = h2 (= flat)

    k_gemm1<<<KCH, 512, 0, stream>>>(bufA, Wp1, part);                 // part = partials (16.4 MB)
    k_reduce<<<dim3(NB * NP / 256, 4), 256, 0, stream>>>(part, hid);
    k_gemm2<<<NP / 64, 256, 0, stream>>>(hid, bp1, Wp2, bp2, out);
}